// Round 4
// baseline (303.318 us; speedup 1.0000x reference)
//
#include <hip/hip_runtime.h>

#define B_TOTAL 2000000
#define NT (B_TOTAL / 4)  // 500000 float4 column-groups per species row

typedef float floatx4 __attribute__((ext_vector_type(4)));

// POLLU RHS, 4 columns per thread.
// conc: [20, B] -> read as float4 (lane stride 16B, 1KB/wave/instr, nontemporal)
// out:  [B, 20] -> each thread owns 4 consecutive columns = 20 contiguous float4s
__global__ __launch_bounds__(256) void pollu_kernel(
    const floatx4* __restrict__ conc4,
    const float* __restrict__ k,
    floatx4* __restrict__ out4)
{
    const int g = blockIdx.x * 256 + threadIdx.x;
    if (g >= NT) return;

    // 20 rows x 4 columns, kept in 80 VGPRs
    floatx4 c4[20];
#pragma unroll
    for (int s = 0; s < 20; ++s)
        c4[s] = __builtin_nontemporal_load(&conc4[(size_t)s * NT + (size_t)g]);

    // wave-uniform -> scalar loads into SGPRs
    const float k1  = k[0],  k2  = k[1],  k3  = k[2],  k4  = k[3],  k5  = k[4];
    const float k6  = k[5],  k7  = k[6],  k8  = k[7],  k9  = k[8],  k10 = k[9];
    const float k11 = k[10], k12 = k[11], k13 = k[12], k14 = k[13], k15 = k[14];
    const float k16 = k[15], k17 = k[16], k18 = k[17], k19 = k[18], k20 = k[19];
    const float k21 = k[20], k22 = k[21], k23 = k[22], k24 = k[23], k25 = k[24];

    const float* cf = (const float*)c4;  // cf[4*s + j] = species s, column j

#pragma unroll
    for (int j = 0; j < 4; ++j) {
        float c[20];
#pragma unroll
        for (int s = 0; s < 20; ++s) c[s] = cf[4 * s + j];

        const float f1  = k1  * c[0];
        const float f2  = k2  * c[1]  * c[3];
        const float f3  = k3  * c[4]  * c[1];
        const float f4  = k4  * c[6];
        const float f5  = k5  * c[6];
        const float f6  = k6  * c[6]  * c[5];
        const float f7  = k7  * c[8];
        const float f8  = k8  * c[8]  * c[5];
        const float f9  = k9  * c[10] * c[1];
        const float f10 = k10 * c[10] * c[0];
        const float f11 = k11 * c[12];
        const float f12 = k12 * c[9]  * c[1];
        const float f13 = k13 * c[13];
        const float f14 = k14 * c[0]  * c[5];
        const float f15 = k15 * c[2];
        const float f16 = k16 * c[3];
        const float f17 = k17 * c[3];
        const float f18 = k18 * c[15];
        const float f19 = k19 * c[15];
        const float f20 = k20 * c[16] * c[5];
        const float f21 = k21 * c[18];
        const float f22 = k22 * c[18];
        const float f23 = k23 * c[0]  * c[3];
        const float f24 = k24 * c[18] * c[0];
        const float f25 = k25 * c[19];

        const float dy0  = -f1 - f10 - f14 - f23 - f24 + f2 + f3 + f9 + f11 + f12 + f22 + f25;
        const float dy1  = -f2 - f3 - f9 - f12 + f1 + f21;
        const float dy2  = -f15 + f1 + f17 + f19 + f22;
        const float dy3  = -f2 - f16 - f17 - f23 + f15;
        const float dy4  = -f3 + 2.0f * f4 + f6 + f7 + f13 + f20;
        const float dy5  = -f6 - f8 - f14 - f20 + f3 + 2.0f * f18;
        const float dy6  = -f4 - f5 - f6 + f13;
        const float dy7  =  f4 + f5 + f6 + f7;
        const float dy8  = -f7 - f8;
        const float dy9  = -f12 + f7 + f9;
        const float dy10 = -f9 - f10 + f8 + f11;
        const float dy11 =  f9;
        const float dy12 = -f11 + f10;
        const float dy13 = -f13 + f12;
        const float dy14 =  f14;
        const float dy15 = -f18 - f19 + f16;
        const float dy16 = -f20;
        const float dy17 =  f20;
        const float dy18 = -f21 - f22 - f24 + f23 + f25;
        const float dy19 = -f25 + f24;

        // columns 4g..4g+3 occupy out float4s [g*20, g*20+20); column j -> 5 float4s
        floatx4* o = out4 + (size_t)g * 20u + (size_t)(5 * j);
        floatx4 o0 = {dy0,  dy1,  dy2,  dy3};
        floatx4 o1 = {dy4,  dy5,  dy6,  dy7};
        floatx4 o2 = {dy8,  dy9,  dy10, dy11};
        floatx4 o3 = {dy12, dy13, dy14, dy15};
        floatx4 o4 = {dy16, dy17, dy18, dy19};
        o[0] = o0;
        o[1] = o1;
        o[2] = o2;
        o[3] = o3;
        o[4] = o4;
    }
}

extern "C" void kernel_launch(void* const* d_in, const int* in_sizes, int n_in,
                              void* d_out, int out_size, void* d_ws, size_t ws_size,
                              hipStream_t stream) {
    // d_in[0] = t (unused), d_in[1] = conc_in [20, B], d_in[2] = k [25]
    const floatx4* conc4 = (const floatx4*)d_in[1];
    const float* k       = (const float*)d_in[2];
    floatx4* out4        = (floatx4*)d_out;

    const int block = 256;
    const int grid  = (NT + block - 1) / block;  // 1954 blocks, last has 32 active threads
    pollu_kernel<<<grid, block, 0, stream>>>(conc4, k, out4);
}